// Round 10
// baseline (418.052 us; speedup 1.0000x reference)
//
#include <hip/hip_runtime.h>
#include <hip/hip_bf16.h>

typedef __bf16 bf16x8 __attribute__((ext_vector_type(8)));
typedef float f32x16 __attribute__((ext_vector_type(16)));

#define DEVI static __device__ __forceinline__

DEVI void load_lds16(const void* g, void* l) {
  __builtin_amdgcn_global_load_lds(
      (const __attribute__((address_space(1))) void*)g,
      (__attribute__((address_space(3))) void*)l, 16, 0, 0);
}

DEVI unsigned short f2b(float f) { return __bfloat16_as_ushort(__float2bfloat16(f)); }
DEVI float b2f(unsigned short u) {
  union { unsigned int i; float f; } c;
  c.i = ((unsigned int)u) << 16;
  return c.f;
}
DEVI float sigm(float x) { return 1.0f / (1.0f + __expf(-x)); }
DEVI float tanh_fast(float x) { return 2.0f / (1.0f + __expf(-2.0f * x)) - 1.0f; }

// involutive 16B-granule swizzle within a 32KB slot: XOR byte-bits 4-6 with bits 7-9.
DEVI int swz(int L) { return L ^ (((L >> 7) & 7) << 4); }

// ---------------------------------------------------------------- fused prep
// blocks [0,4096): cast x -> xb ; [4096,8192): perm-cast W -> Wbp ;
// [8192,12288): perm-cast U -> Ubp ; [12288,12304): bp = bW+bU (permuted)
__global__ __launch_bounds__(256) void prep_kernel(
    const float* __restrict__ x, const float* __restrict__ W,
    const float* __restrict__ U, const float* __restrict__ bW,
    const float* __restrict__ bU, unsigned short* __restrict__ xb,
    unsigned short* __restrict__ Wbp, unsigned short* __restrict__ Ubp,
    float* __restrict__ bp) {
  const int bid = blockIdx.x;
  if (bid < 4096) {
    const int i = bid * 256 + threadIdx.x;
    const float4 v = reinterpret_cast<const float4*>(x)[i];
    ushort4 o;
    o.x = f2b(v.x); o.y = f2b(v.y); o.z = f2b(v.z); o.w = f2b(v.w);
    reinterpret_cast<ushort4*>(xb)[i] = o;
  } else if (bid < 12288) {
    const bool isW = bid < 8192;
    const float* src = isW ? W : U;
    unsigned short* dst = isW ? Wbp : Ubp;
    const int i = (bid - (isW ? 4096 : 8192)) * 256 + threadIdx.x;
    const int r = i >> 8;
    const int cw = i & 255;
    const float4 v = reinterpret_cast<const float4*>(src)[i];
    const int rp = ((r & 1023) << 2) + (r >> 10);  // 4h+g
    ushort4 o;
    o.x = f2b(v.x); o.y = f2b(v.y); o.z = f2b(v.z); o.w = f2b(v.w);
    *reinterpret_cast<ushort4*>(&dst[(size_t)rp * 1024 + (cw << 2)]) = o;
  } else {
    const int i = (bid - 12288) * 256 + threadIdx.x;  // 0..4095
    const int h = i >> 2, g = i & 3;
    bp[i] = bW[g * 1024 + h] + bU[g * 1024 + h];
  }
}

// one K-phase (K=32, two 32x32x16 k-substeps): MFMA on current frags ||
// ds_read next frags || stage slot p+4. af progressively overwritten
// (af[m] dead after its 4 MFMAs); bf double-buffered.
#define KPHASE(BFC, BFN, SLNXT, STAGEQ, DOSTAGE, WAITSTR, DOBAR)              \
  {                                                                           \
    if (DOSTAGE) STAGE(STAGEQ);                                               \
    const unsigned char* sln_ = (SLNXT);                                      \
    _Pragma("unroll") for (int n_ = 0; n_ < 2; ++n_)                          \
      _Pragma("unroll") for (int k_ = 0; k_ < 2; ++k_)                        \
        BFN[n_][k_] = *reinterpret_cast<const bf16x8*>(sln_ + offB[n_][k_]);  \
    __builtin_amdgcn_s_setprio(1);                                            \
    _Pragma("unroll") for (int m_ = 0; m_ < 4; ++m_) {                        \
      acc[m_][0] = __builtin_amdgcn_mfma_f32_32x32x16_bf16(af[m_][0], BFC[0][0], acc[m_][0], 0, 0, 0); \
      acc[m_][0] = __builtin_amdgcn_mfma_f32_32x32x16_bf16(af[m_][1], BFC[0][1], acc[m_][0], 0, 0, 0); \
      acc[m_][1] = __builtin_amdgcn_mfma_f32_32x32x16_bf16(af[m_][0], BFC[1][0], acc[m_][1], 0, 0, 0); \
      acc[m_][1] = __builtin_amdgcn_mfma_f32_32x32x16_bf16(af[m_][1], BFC[1][1], acc[m_][1], 0, 0, 0); \
      af[m_][0] = *reinterpret_cast<const bf16x8*>(sln_ + offA[m_][0]);       \
      af[m_][1] = *reinterpret_cast<const bf16x8*>(sln_ + offA[m_][1]);       \
    }                                                                         \
    __builtin_amdgcn_s_setprio(0);                                            \
    asm volatile(WAITSTR ::: "memory");                                       \
    __builtin_amdgcn_sched_barrier(0);                                        \
    if (DOBAR) {                                                              \
      __builtin_amdgcn_s_barrier();                                           \
      __builtin_amdgcn_sched_barrier(0);                                      \
    }                                                                         \
  }

// ---------------------------------------------------------------- GEMM 256x256 + fused LSTM gates
// proj = A[4096,1024] * Bm[4096,1024]^T (bf16 in, fp32 acc). 4 LDS slots x 32KB,
// counted vmcnt(8) (slots {p+2,p+3} in flight), reg-dbuf pipeline (R9 ledger),
// 32x32x16 MFMA: per-wave 128x64 = acc[4][2] f32x16.
// Epilogue (verified R7): LDS-stage bf16 tile stride 264, fused gates by MODE.
template <int MODE>
__global__ __launch_bounds__(512, 2) void gemm256(
    const unsigned short* __restrict__ A,
    const unsigned short* __restrict__ Bm,
    const unsigned short* __restrict__ xpb_r,  // MID/LAST: [B,4H] bf16 (proj+bias)
    unsigned short* __restrict__ xpb_w,        // FIRST: write
    const float* __restrict__ bp,              // FIRST: [4H] combined bias
    unsigned short* __restrict__ ct,           // [B,H] bf16 state (rw)
    unsigned short* __restrict__ htout,        // [B,H] bf16 next-step input
    float* __restrict__ out) {                 // d_out when LAST
  constexpr int K = 1024, N = 4096;
  __shared__ unsigned char lds[256 * 528];  // 135168 B >= 4*32768 K-loop use

  const int tid = threadIdx.x;
  const int lane = tid & 63;
  const int wave = tid >> 6;
  const int wr = wave >> 2;  // 0..1 : M half (128 rows)
  const int wc = wave & 3;   // 0..3 : N quarter (64 cols)

  // XCD-aware block swizzle (nwg=256, divisible by 8)
  const int bid = blockIdx.x;
  const int sw = (bid & 7) * 32 + (bid >> 3);
  const int brow = (sw >> 4) * 256;
  const int bcol = (sw & 15) * 256;

  // staging geometry (swizzle via pre-permuted global source, rule #21)
  const int physA0 = tid * 16;
  const int physA1 = 8192 + tid * 16;
  const int physB0 = 16384 + tid * 16;
  const int physB1 = 24576 + tid * 16;
  const int LA0 = swz(physA0), LA1 = swz(physA1);
  const int LB0 = swz(physB0 - 16384), LB1 = swz(physB1 - 16384);
  const unsigned char* pA0 = (const unsigned char*)A + (size_t)(brow + (LA0 >> 6)) * (K * 2) + (LA0 & 63);
  const unsigned char* pA1 = (const unsigned char*)A + (size_t)(brow + (LA1 >> 6)) * (K * 2) + (LA1 & 63);
  const unsigned char* pB0 = (const unsigned char*)Bm + (size_t)(bcol + (LB0 >> 6)) * (K * 2) + (LB0 & 63);
  const unsigned char* pB1 = (const unsigned char*)Bm + (size_t)(bcol + (LB1 >> 6)) * (K * 2) + (LB1 & 63);

  // fragment read offsets (slot-relative), swizzled. 32x32x16 operand layout:
  // A: row = lane&31, k = (lane>>5)*8 + i  (ksub selects k 0-15 / 16-31 of the phase)
  const int kq = (lane >> 5) * 16;  // 16B half within a 32B ksub block
  int offA[4][2], offB[2][2];
#pragma unroll
  for (int m = 0; m < 4; ++m)
#pragma unroll
    for (int ks = 0; ks < 2; ++ks) {
      const int row = wr * 128 + m * 32 + (lane & 31);
      offA[m][ks] = swz(row * 64 + ks * 32 + kq);
    }
#pragma unroll
  for (int n = 0; n < 2; ++n)
#pragma unroll
    for (int ks = 0; ks < 2; ++ks) {
      const int row = wc * 64 + n * 32 + (lane & 31);
      offB[n][ks] = 16384 + swz(row * 64 + ks * 32 + kq);
    }

  f32x16 acc[4][2] = {};
  bf16x8 af[4][2], bfE[2][2], bfO[2][2];

  auto STAGE = [&](int q) {
    unsigned char* sb = lds + (q & 3) * 32768;
    const size_t kb = (size_t)q * 64;
    load_lds16(pA0 + kb, sb + physA0);
    load_lds16(pA1 + kb, sb + physA1);
    load_lds16(pB0 + kb, sb + physB0);
    load_lds16(pB1 + kb, sb + physB1);
  };

  // prologue: 4 slots in flight (16 loads); vmcnt(8) retires slots 0,1
  STAGE(0); STAGE(1); STAGE(2); STAGE(3);
  asm volatile("s_waitcnt vmcnt(8)" ::: "memory");
  __builtin_amdgcn_s_barrier();
  // preload frags(0) from slot 0
#pragma unroll
  for (int n = 0; n < 2; ++n)
#pragma unroll
    for (int ks = 0; ks < 2; ++ks)
      bfE[n][ks] = *reinterpret_cast<const bf16x8*>(lds + offB[n][ks]);
#pragma unroll
  for (int m = 0; m < 4; ++m)
#pragma unroll
    for (int ks = 0; ks < 2; ++ks)
      af[m][ks] = *reinterpret_cast<const bf16x8*>(lds + offA[m][ks]);
  asm volatile("s_waitcnt lgkmcnt(0)" ::: "memory");
  __builtin_amdgcn_sched_barrier(0);
  __builtin_amdgcn_s_barrier();  // protect slot 0 from phase-0's STAGE(4)
  __builtin_amdgcn_sched_barrier(0);

  // phases 0..27 (uniform): stage p+4, vmcnt(8)
  for (int pp = 0; pp < 14; ++pp) {
    const int p = 2 * pp;
    const unsigned char* sl1 = lds + ((p + 1) & 3) * 32768;
    const unsigned char* sl2 = lds + ((p + 2) & 3) * 32768;
    KPHASE(bfE, bfO, sl1, p + 4, true, "s_waitcnt vmcnt(8) lgkmcnt(0)", true);
    KPHASE(bfO, bfE, sl2, p + 5, true, "s_waitcnt vmcnt(8) lgkmcnt(0)", true);
  }
  // phase 28: no stage, vmcnt(4) retires slot 30
  KPHASE(bfE, bfO, lds + (29 & 3) * 32768, 0, false, "s_waitcnt vmcnt(4) lgkmcnt(0)", true);
  // phase 29: no stage, vmcnt(0) retires slot 31
  KPHASE(bfO, bfE, lds + (30 & 3) * 32768, 0, false, "s_waitcnt vmcnt(0) lgkmcnt(0)", true);
  // phase 30: reads frags(31), lgkm only, no barrier (no pending LDS writes)
  KPHASE(bfE, bfO, lds + (31 & 3) * 32768, 0, false, "s_waitcnt lgkmcnt(0)", false);
  // phase 31: MFMA only
  __builtin_amdgcn_s_setprio(1);
#pragma unroll
  for (int m = 0; m < 4; ++m) {
    acc[m][0] = __builtin_amdgcn_mfma_f32_32x32x16_bf16(af[m][0], bfO[0][0], acc[m][0], 0, 0, 0);
    acc[m][0] = __builtin_amdgcn_mfma_f32_32x32x16_bf16(af[m][1], bfO[0][1], acc[m][0], 0, 0, 0);
    acc[m][1] = __builtin_amdgcn_mfma_f32_32x32x16_bf16(af[m][0], bfO[1][0], acc[m][1], 0, 0, 0);
    acc[m][1] = __builtin_amdgcn_mfma_f32_32x32x16_bf16(af[m][1], bfO[1][1], acc[m][1], 0, 0, 0);
  }
  __builtin_amdgcn_s_setprio(0);

  // ---- epilogue: stage bf16 proj tile into LDS, padded row stride 264 elems
  // 32x32 C/D layout (m74/m101): col = lane&31, row = (r&3) + 8*(r>>2) + 4*(lane>>5)
  __syncthreads();
  unsigned short* cs = (unsigned short*)lds;
  {
    const int c0 = wc * 64 + (lane & 31);
    const int rb = wr * 128 + 4 * (lane >> 5);
#pragma unroll
    for (int m = 0; m < 4; ++m)
#pragma unroll
      for (int n = 0; n < 2; ++n) {
        const int cc = c0 + n * 32;
#pragma unroll
        for (int r = 0; r < 16; ++r) {
          const int rr = rb + m * 32 + (r & 3) + 8 * (r >> 2);
          cs[rr * 264 + cc] = f2b(acc[m][n][r]);
        }
      }
  }
  __syncthreads();

  // ---- fused gates: 256 rows x 64 h per block
  const int hbase = bcol >> 2;
#pragma unroll 4
  for (int j = 0; j < 32; ++j) {
    const int q = tid + (j << 9);  // 0..16383
    const int row = q >> 6;
    const int hh = q & 63;
    const ushort4 pv = *reinterpret_cast<const ushort4*>(&cs[row * 264 + hh * 4]);
    const int ci = (brow + row) * 1024 + hbase + hh;
    float sf, si, so, sg;
    if constexpr (MODE == 0) {
      const float4 bpv = *reinterpret_cast<const float4*>(&bp[bcol + hh * 4]);
      sf = b2f(pv.x) + bpv.x;
      si = b2f(pv.y) + bpv.y;
      so = b2f(pv.z) + bpv.z;
      sg = b2f(pv.w) + bpv.w;
      ushort4 xo;
      xo.x = f2b(sf); xo.y = f2b(si); xo.z = f2b(so); xo.w = f2b(sg);
      *reinterpret_cast<ushort4*>(&xpb_w[(size_t)(brow + row) * N + bcol + hh * 4]) = xo;
    } else {
      const ushort4 xv = *reinterpret_cast<const ushort4*>(&xpb_r[(size_t)(brow + row) * N + bcol + hh * 4]);
      sf = b2f(pv.x) + b2f(xv.x);
      si = b2f(pv.y) + b2f(xv.y);
      so = b2f(pv.z) + b2f(xv.z);
      sg = b2f(pv.w) + b2f(xv.w);
    }
    const float c_old = (MODE == 0) ? 0.0f : b2f(ct[ci]);
    const float f = sigm(sf);
    const float ii = sigm(si);
    const float o = sigm(so);
    const float gg = tanh_fast(sg);
    const float c = fmaf(f, c_old, ii * gg);
    const float h = o * tanh_fast(c);
    if constexpr (MODE == 2) {
      out[ci] = h;
      out[4194304 + ci] = c;
    } else {
      ct[ci] = f2b(c);
      htout[ci] = f2b(h);
    }
  }
}

// ---------------------------------------------------------------- launch
extern "C" void kernel_launch(void* const* d_in, const int* in_sizes, int n_in,
                              void* d_out, int out_size, void* d_ws, size_t ws_size,
                              hipStream_t stream) {
  const float* x = (const float*)d_in[0];   // [4096,1024]
  const float* W = (const float*)d_in[1];   // [4096,1024]
  const float* bW = (const float*)d_in[2];  // [4096]
  const float* U = (const float*)d_in[3];   // [4096,1024]
  const float* bU = (const float*)d_in[4];  // [4096]
  float* out = (float*)d_out;

  char* w = (char*)d_ws;
  const size_t MB = 1ull << 20;
  unsigned short* xb = (unsigned short*)(w + 0 * MB);    // 8 MB
  unsigned short* Wbp = (unsigned short*)(w + 8 * MB);   // 8 MB (gate-interleaved)
  unsigned short* Ubp = (unsigned short*)(w + 16 * MB);  // 8 MB (gate-interleaved)
  unsigned short* xpb = (unsigned short*)(w + 24 * MB);  // 32 MB [B,4H] bf16 proj+bias
  unsigned short* ct = (unsigned short*)(w + 56 * MB);   // 8 MB bf16 state
  unsigned short* htA = (unsigned short*)(w + 64 * MB);  // 8 MB
  unsigned short* htB = (unsigned short*)(w + 72 * MB);  // 8 MB
  float* bp = (float*)(w + 80 * MB);                     // 16 KB

  prep_kernel<<<12304, 256, 0, stream>>>(x, W, U, bW, bU, xb, Wbp, Ubp, bp);

  // step 0: x-projection GEMM with fused gates (c0 = 0), writes xpb + ct + htA
  gemm256<0><<<256, 512, 0, stream>>>(xb, Wbp, nullptr, xpb, bp, ct, htA, nullptr);

  const unsigned short* hin = htA;
  unsigned short* hout = htB;
  for (int t = 1; t <= 6; ++t) {
    gemm256<1><<<256, 512, 0, stream>>>(hin, Ubp, xpb, nullptr, nullptr, ct, hout, nullptr);
    const unsigned short* tmp = hout;
    hout = (unsigned short*)hin;
    hin = tmp;
  }
  gemm256<2><<<256, 512, 0, stream>>>(hin, Ubp, xpb, nullptr, nullptr, ct, nullptr, out);
}

// Round 11
// 370.403 us; speedup vs baseline: 1.1286x; 1.1286x over previous
//
#include <hip/hip_runtime.h>
#include <hip/hip_bf16.h>

typedef __bf16 bf16x8 __attribute__((ext_vector_type(8)));
typedef float f32x4 __attribute__((ext_vector_type(4)));

#define DEVI static __device__ __forceinline__

DEVI void load_lds16(const void* g, void* l) {
  __builtin_amdgcn_global_load_lds(
      (const __attribute__((address_space(1))) void*)g,
      (__attribute__((address_space(3))) void*)l, 16, 0, 0);
}

DEVI unsigned short f2b(float f) { return __bfloat16_as_ushort(__float2bfloat16(f)); }
DEVI float b2f(unsigned short u) {
  union { unsigned int i; float f; } c;
  c.i = ((unsigned int)u) << 16;
  return c.f;
}
DEVI float sigm(float x) { return 1.0f / (1.0f + __expf(-x)); }
DEVI float tanh_fast(float x) { return 2.0f / (1.0f + __expf(-2.0f * x)) - 1.0f; }

// involutive 16B-granule swizzle within a 32KB slot: XOR byte-bits 4-6 with bits 7-9.
// Verified conflict-free for the 16-row 16x16 fragment reads (R3-R9); NOT for 32-row reads (R10).
DEVI int swz(int L) { return L ^ (((L >> 7) & 7) << 4); }

// ---------------------------------------------------------------- fused prep
// blocks [0,4096): cast x -> xb ; [4096,8192): perm-cast W -> Wbp ;
// [8192,12288): perm-cast U -> Ubp ; [12288,12304): bp = bW+bU (permuted)
__global__ __launch_bounds__(256) void prep_kernel(
    const float* __restrict__ x, const float* __restrict__ W,
    const float* __restrict__ U, const float* __restrict__ bW,
    const float* __restrict__ bU, unsigned short* __restrict__ xb,
    unsigned short* __restrict__ Wbp, unsigned short* __restrict__ Ubp,
    float* __restrict__ bp) {
  const int bid = blockIdx.x;
  if (bid < 4096) {
    const int i = bid * 256 + threadIdx.x;
    const float4 v = reinterpret_cast<const float4*>(x)[i];
    ushort4 o;
    o.x = f2b(v.x); o.y = f2b(v.y); o.z = f2b(v.z); o.w = f2b(v.w);
    reinterpret_cast<ushort4*>(xb)[i] = o;
  } else if (bid < 12288) {
    const bool isW = bid < 8192;
    const float* src = isW ? W : U;
    unsigned short* dst = isW ? Wbp : Ubp;
    const int i = (bid - (isW ? 4096 : 8192)) * 256 + threadIdx.x;
    const int r = i >> 8;
    const int cw = i & 255;
    const float4 v = reinterpret_cast<const float4*>(src)[i];
    const int rp = ((r & 1023) << 2) + (r >> 10);  // 4h+g
    ushort4 o;
    o.x = f2b(v.x); o.y = f2b(v.y); o.z = f2b(v.z); o.w = f2b(v.w);
    *reinterpret_cast<ushort4*>(&dst[(size_t)rp * 1024 + (cw << 2)]) = o;
  } else {
    const int i = (bid - 12288) * 256 + threadIdx.x;  // 0..4095
    const int h = i >> 2, g = i & 3;
    bp[i] = bW[g * 1024 + h] + bU[g * 1024 + h];
  }
}

// one K-phase: MFMA on current frags || ds_read next frags || stage slot p+4.
// af progressively overwritten (af[m] dead after its 4 MFMAs); bf double-buffered.
#define KPHASE(BFC, BFN, SLNXT, STAGEQ, DOSTAGE, WAITSTR, DOBAR)              \
  {                                                                           \
    if (DOSTAGE) STAGE(STAGEQ);                                               \
    const unsigned char* sln_ = (SLNXT);                                      \
    _Pragma("unroll") for (int n_ = 0; n_ < 4; ++n_)                          \
        BFN[n_] = *reinterpret_cast<const bf16x8*>(sln_ + offB[n_]);          \
    __builtin_amdgcn_s_setprio(1);                                            \
    _Pragma("unroll") for (int m_ = 0; m_ < 8; ++m_) {                        \
      _Pragma("unroll") for (int n_ = 0; n_ < 4; ++n_)                        \
          acc[m_][n_] = __builtin_amdgcn_mfma_f32_16x16x32_bf16(              \
              af[m_], BFC[n_], acc[m_][n_], 0, 0, 0);                         \
      af[m_] = *reinterpret_cast<const bf16x8*>(sln_ + offA[m_]);             \
    }                                                                         \
    __builtin_amdgcn_s_setprio(0);                                            \
    asm volatile(WAITSTR ::: "memory");                                       \
    __builtin_amdgcn_sched_barrier(0);                                        \
    if (DOBAR) {                                                              \
      __builtin_amdgcn_s_barrier();                                           \
      __builtin_amdgcn_sched_barrier(0);                                      \
    }                                                                         \
  }

// ---------------------------------------------------------------- GEMM 256x256 + fused LSTM gates
// proj = A[4096,1024] * Bm[4096,1024]^T (bf16 in, fp32 acc). 4 LDS slots x 32KB,
// counted vmcnt(8) (slots {p+2,p+3} in flight), reg-dbuf pipeline (R9 ledger).
// Epilogue: LDS-stage bf16 tile stride 264, vectorized fused gates by MODE.
template <int MODE>
__global__ __launch_bounds__(512, 2) void gemm256(
    const unsigned short* __restrict__ A,
    const unsigned short* __restrict__ Bm,
    const unsigned short* __restrict__ xpb_r,  // MID/LAST: [B,4H] bf16 (proj+bias)
    unsigned short* __restrict__ xpb_w,        // FIRST: write
    const float* __restrict__ bp,              // FIRST: [4H] combined bias
    unsigned short* __restrict__ ct,           // [B,H] bf16 state (rw)
    unsigned short* __restrict__ htout,        // [B,H] bf16 next-step input
    float* __restrict__ out) {                 // d_out when LAST
  constexpr int K = 1024, N = 4096;
  __shared__ unsigned char lds[256 * 528];  // 135168 B >= 4*32768 K-loop use

  const int tid = threadIdx.x;
  const int lane = tid & 63;
  const int wave = tid >> 6;
  const int wr = wave >> 2;  // 0..1 : M half (128 rows)
  const int wc = wave & 3;   // 0..3 : N quarter (64 cols)

  // XCD-aware block swizzle (nwg=256, divisible by 8)
  const int bid = blockIdx.x;
  const int sw = (bid & 7) * 32 + (bid >> 3);
  const int brow = (sw >> 4) * 256;
  const int bcol = (sw & 15) * 256;

  // staging geometry (swizzle via pre-permuted global source, rule #21)
  const int physA0 = tid * 16;
  const int physA1 = 8192 + tid * 16;
  const int physB0 = 16384 + tid * 16;
  const int physB1 = 24576 + tid * 16;
  const int LA0 = swz(physA0), LA1 = swz(physA1);
  const int LB0 = swz(physB0 - 16384), LB1 = swz(physB1 - 16384);
  const unsigned char* pA0 = (const unsigned char*)A + (size_t)(brow + (LA0 >> 6)) * (K * 2) + (LA0 & 63);
  const unsigned char* pA1 = (const unsigned char*)A + (size_t)(brow + (LA1 >> 6)) * (K * 2) + (LA1 & 63);
  const unsigned char* pB0 = (const unsigned char*)Bm + (size_t)(bcol + (LB0 >> 6)) * (K * 2) + (LB0 & 63);
  const unsigned char* pB1 = (const unsigned char*)Bm + (size_t)(bcol + (LB1 >> 6)) * (K * 2) + (LB1 & 63);

  // fragment read offsets (slot-relative), swizzled
  const int s16 = (lane >> 4) * 16;
  int offA[8], offB[4];
#pragma unroll
  for (int m = 0; m < 8; ++m) {
    const int row = wr * 128 + m * 16 + (lane & 15);
    offA[m] = swz(row * 64 + s16);
  }
#pragma unroll
  for (int n = 0; n < 4; ++n) {
    const int row = wc * 64 + n * 16 + (lane & 15);
    offB[n] = 16384 + swz(row * 64 + s16);
  }

  f32x4 acc[8][4] = {};
  bf16x8 af[8], bfE[4], bfO[4];

  auto STAGE = [&](int q) {
    unsigned char* sb = lds + (q & 3) * 32768;
    const size_t kb = (size_t)q * 64;
    load_lds16(pA0 + kb, sb + physA0);
    load_lds16(pA1 + kb, sb + physA1);
    load_lds16(pB0 + kb, sb + physB0);
    load_lds16(pB1 + kb, sb + physB1);
  };

  // prologue: 4 slots in flight (16 loads); vmcnt(8) retires slots 0,1
  STAGE(0); STAGE(1); STAGE(2); STAGE(3);
  asm volatile("s_waitcnt vmcnt(8)" ::: "memory");
  __builtin_amdgcn_s_barrier();
  // preload frags(0) from slot 0
#pragma unroll
  for (int n = 0; n < 4; ++n) bfE[n] = *reinterpret_cast<const bf16x8*>(lds + offB[n]);
#pragma unroll
  for (int m = 0; m < 8; ++m) af[m] = *reinterpret_cast<const bf16x8*>(lds + offA[m]);
  asm volatile("s_waitcnt lgkmcnt(0)" ::: "memory");
  __builtin_amdgcn_sched_barrier(0);
  __builtin_amdgcn_s_barrier();  // protect slot 0 from phase-0's STAGE(4)
  __builtin_amdgcn_sched_barrier(0);

  // phases 0..27 (uniform): stage p+4, vmcnt(8)
  for (int pp = 0; pp < 14; ++pp) {
    const int p = 2 * pp;
    const unsigned char* sl1 = lds + ((p + 1) & 3) * 32768;
    const unsigned char* sl2 = lds + ((p + 2) & 3) * 32768;
    KPHASE(bfE, bfO, sl1, p + 4, true, "s_waitcnt vmcnt(8) lgkmcnt(0)", true);
    KPHASE(bfO, bfE, sl2, p + 5, true, "s_waitcnt vmcnt(8) lgkmcnt(0)", true);
  }
  // phase 28: no stage, vmcnt(4) retires slot 30
  KPHASE(bfE, bfO, lds + (29 & 3) * 32768, 0, false, "s_waitcnt vmcnt(4) lgkmcnt(0)", true);
  // phase 29: no stage, vmcnt(0) retires slot 31
  KPHASE(bfO, bfE, lds + (30 & 3) * 32768, 0, false, "s_waitcnt vmcnt(0) lgkmcnt(0)", true);
  // phase 30: reads frags(31), lgkm only, no barrier (no pending LDS writes)
  KPHASE(bfE, bfO, lds + (31 & 3) * 32768, 0, false, "s_waitcnt lgkmcnt(0)", false);
  // phase 31: MFMA only
  __builtin_amdgcn_s_setprio(1);
#pragma unroll
  for (int m = 0; m < 8; ++m)
#pragma unroll
    for (int n = 0; n < 4; ++n)
      acc[m][n] = __builtin_amdgcn_mfma_f32_16x16x32_bf16(af[m], bfO[n], acc[m][n], 0, 0, 0);
  __builtin_amdgcn_s_setprio(0);

  // ---- epilogue: stage bf16 proj tile into LDS, padded row stride 264 elems
  __syncthreads();
  unsigned short* cs = (unsigned short*)lds;
  {
    const int c0 = wc * 64 + (lane & 15);
    const int r00 = wr * 128 + ((lane >> 4) << 2);
#pragma unroll
    for (int m = 0; m < 8; ++m)
#pragma unroll
      for (int n = 0; n < 4; ++n) {
        const int rr = r00 + m * 16;
        const int cc = c0 + n * 16;
#pragma unroll
        for (int r = 0; r < 4; ++r) cs[(rr + r) * 264 + cc] = f2b(acc[m][n][r]);
      }
  }
  __syncthreads();

  // ---- fused gates, vectorized: thread -> (row, 4 consecutive h). 8 iters.
  const int hbase = bcol >> 2;
#pragma unroll 2
  for (int j = 0; j < 8; ++j) {
    const int v = tid + (j << 9);   // 0..4095
    const int row = v >> 4;         // 0..255
    const int h4 = (v & 15) << 2;   // 0,4,...,60
    const int ci = (brow + row) * 1024 + hbase + h4;

    // 32B of cs: gate quads for h4..h4+3 (per-lane contiguous)
    unsigned short pvv[16];
    *reinterpret_cast<uint4*>(&pvv[0]) = *reinterpret_cast<const uint4*>(&cs[row * 264 + h4 * 4]);
    *reinterpret_cast<uint4*>(&pvv[8]) = *reinterpret_cast<const uint4*>(&cs[row * 264 + h4 * 4 + 8]);

    float sf[4], si_[4], so_[4], sg_[4];
    if constexpr (MODE == 0) {
      float bpf[16];
#pragma unroll
      for (int q = 0; q < 4; ++q)
        *reinterpret_cast<float4*>(&bpf[q * 4]) =
            *reinterpret_cast<const float4*>(&bp[bcol + h4 * 4 + q * 4]);
#pragma unroll
      for (int k = 0; k < 4; ++k) {
        sf[k] = b2f(pvv[4 * k + 0]) + bpf[4 * k + 0];
        si_[k] = b2f(pvv[4 * k + 1]) + bpf[4 * k + 1];
        so_[k] = b2f(pvv[4 * k + 2]) + bpf[4 * k + 2];
        sg_[k] = b2f(pvv[4 * k + 3]) + bpf[4 * k + 3];
      }
      unsigned short xo[16];
#pragma unroll
      for (int k = 0; k < 4; ++k) {
        xo[4 * k + 0] = f2b(sf[k]);
        xo[4 * k + 1] = f2b(si_[k]);
        xo[4 * k + 2] = f2b(so_[k]);
        xo[4 * k + 3] = f2b(sg_[k]);
      }
      unsigned short* xw = &xpb_w[(size_t)(brow + row) * N + bcol + h4 * 4];
      *reinterpret_cast<uint4*>(xw) = *reinterpret_cast<const uint4*>(&xo[0]);
      *reinterpret_cast<uint4*>(xw + 8) = *reinterpret_cast<const uint4*>(&xo[8]);
    } else {
      unsigned short xvv[16];
      const unsigned short* xr = &xpb_r[(size_t)(brow + row) * N + bcol + h4 * 4];
      *reinterpret_cast<uint4*>(&xvv[0]) = *reinterpret_cast<const uint4*>(xr);
      *reinterpret_cast<uint4*>(&xvv[8]) = *reinterpret_cast<const uint4*>(xr + 8);
#pragma unroll
      for (int k = 0; k < 4; ++k) {
        sf[k] = b2f(pvv[4 * k + 0]) + b2f(xvv[4 * k + 0]);
        si_[k] = b2f(pvv[4 * k + 1]) + b2f(xvv[4 * k + 1]);
        so_[k] = b2f(pvv[4 * k + 2]) + b2f(xvv[4 * k + 2]);
        sg_[k] = b2f(pvv[4 * k + 3]) + b2f(xvv[4 * k + 3]);
      }
    }

    float c_old[4] = {0.f, 0.f, 0.f, 0.f};
    if constexpr (MODE != 0) {
      const ushort4 cv = *reinterpret_cast<const ushort4*>(&ct[ci]);
      c_old[0] = b2f(cv.x); c_old[1] = b2f(cv.y);
      c_old[2] = b2f(cv.z); c_old[3] = b2f(cv.w);
    }

    float cn[4], hn[4];
#pragma unroll
    for (int k = 0; k < 4; ++k) {
      const float f = sigm(sf[k]);
      const float ii = sigm(si_[k]);
      const float o = sigm(so_[k]);
      const float gg = tanh_fast(sg_[k]);
      const float c = fmaf(f, c_old[k], ii * gg);
      cn[k] = c;
      hn[k] = o * tanh_fast(c);
    }

    if constexpr (MODE == 2) {
      *reinterpret_cast<float4*>(&out[ci]) = make_float4(hn[0], hn[1], hn[2], hn[3]);
      *reinterpret_cast<float4*>(&out[4194304 + ci]) = make_float4(cn[0], cn[1], cn[2], cn[3]);
    } else {
      ushort4 cb, hb;
      cb.x = f2b(cn[0]); cb.y = f2b(cn[1]); cb.z = f2b(cn[2]); cb.w = f2b(cn[3]);
      hb.x = f2b(hn[0]); hb.y = f2b(hn[1]); hb.z = f2b(hn[2]); hb.w = f2b(hn[3]);
      *reinterpret_cast<ushort4*>(&ct[ci]) = cb;
      *reinterpret_cast<ushort4*>(&htout[ci]) = hb;
    }
  }
}

// ---------------------------------------------------------------- launch
extern "C" void kernel_launch(void* const* d_in, const int* in_sizes, int n_in,
                              void* d_out, int out_size, void* d_ws, size_t ws_size,
                              hipStream_t stream) {
  const float* x = (const float*)d_in[0];   // [4096,1024]
  const float* W = (const float*)d_in[1];   // [4096,1024]
  const float* bW = (const float*)d_in[2];  // [4096]
  const float* U = (const float*)d_in[3];   // [4096,1024]
  const float* bU = (const float*)d_in[4];  // [4096]
  float* out = (float*)d_out;

  char* w = (char*)d_ws;
  const size_t MB = 1ull << 20;
  unsigned short* xb = (unsigned short*)(w + 0 * MB);    // 8 MB
  unsigned short* Wbp = (unsigned short*)(w + 8 * MB);   // 8 MB (gate-interleaved)
  unsigned short* Ubp = (unsigned short*)(w + 16 * MB);  // 8 MB (gate-interleaved)
  unsigned short* xpb = (unsigned short*)(w + 24 * MB);  // 32 MB [B,4H] bf16 proj+bias
  unsigned short* ct = (unsigned short*)(w + 56 * MB);   // 8 MB bf16 state
  unsigned short* htA = (unsigned short*)(w + 64 * MB);  // 8 MB
  unsigned short* htB = (unsigned short*)(w + 72 * MB);  // 8 MB
  float* bp = (float*)(w + 80 * MB);                     // 16 KB

  prep_kernel<<<12304, 256, 0, stream>>>(x, W, U, bW, bU, xb, Wbp, Ubp, bp);

  // step 0: x-projection GEMM with fused gates (c0 = 0), writes xpb + ct + htA
  gemm256<0><<<256, 512, 0, stream>>>(xb, Wbp, nullptr, xpb, bp, ct, htA, nullptr);

  const unsigned short* hin = htA;
  unsigned short* hout = htB;
  for (int t = 1; t <= 6; ++t) {
    gemm256<1><<<256, 512, 0, stream>>>(hin, Ubp, xpb, nullptr, nullptr, ct, hout, nullptr);
    const unsigned short* tmp = hout;
    hout = (unsigned short*)hin;
    hin = tmp;
  }
  gemm256<2><<<256, 512, 0, stream>>>(hin, Ubp, xpb, nullptr, nullptr, ct, nullptr, out);
}

// Round 12
// 360.342 us; speedup vs baseline: 1.1602x; 1.0279x over previous
//
#include <hip/hip_runtime.h>
#include <hip/hip_bf16.h>

typedef __bf16 bf16x8 __attribute__((ext_vector_type(8)));
typedef float f32x4 __attribute__((ext_vector_type(4)));
typedef long i64x2 __attribute__((ext_vector_type(2)));

#define DEVI static __device__ __forceinline__

DEVI void load_lds16(const void* g, void* l) {
  __builtin_amdgcn_global_load_lds(
      (const __attribute__((address_space(1))) void*)g,
      (__attribute__((address_space(3))) void*)l, 16, 0, 0);
}

DEVI unsigned short f2b(float f) { return __bfloat16_as_ushort(__float2bfloat16(f)); }
DEVI float b2f(unsigned short u) {
  union { unsigned int i; float f; } c;
  c.i = ((unsigned int)u) << 16;
  return c.f;
}
DEVI float sigm(float x) { return 1.0f / (1.0f + __expf(-x)); }
DEVI float tanh_fast(float x) { return 2.0f / (1.0f + __expf(-2.0f * x)) - 1.0f; }

// float -> OCP e4m3fn with RNE (hand-rolled; sat to 448, subnormals handled)
DEVI unsigned char f2fp8(float f) {
  const unsigned int u = __float_as_uint(f);
  const unsigned char s = (unsigned char)((u >> 24) & 0x80);
  const float a = fabsf(f);
  if (a >= 448.f) return s | 0x7E;
  if (a < 0.015625f) {  // subnormal range: value = M * 2^-9
    const int M = (int)rintf(a * 512.f);
    if (M > 7) return s | 0x08;  // rounds up to min normal
    return s | (unsigned char)M;
  }
  int ex;
  const float m = frexpf(a, &ex);      // a = m*2^ex, m in [0.5,1)
  int r = (int)rintf(m * 16.f);        // [8,16]
  if (r == 16) { r = 8; ex += 1; }
  const int E = ex + 6, M = r - 8;     // value = (1+M/8)*2^(E-7)
  if (E > 15 || (E == 15 && M == 7)) return s | 0x7E;
  return s | (unsigned char)((E << 3) | M);
}

// involutive 16B-granule swizzle (64B rows): XOR byte-bits 4-6 with bits 7-9.
// Verified conflict-free for the 16-row fragment/staging patterns (R3-R11).
DEVI int swz(int L) { return L ^ (((L >> 7) & 7) << 4); }

// fp8 image k-index: true col hc -> image byte. Per 64-col pair-tile:
// granule q=(hc&31)>>3 holds [tile-even k 8q..8q+7 | tile-odd +32..].
DEVI int imgk(int hc) {
  return (hc & ~63) + (((hc >> 3) & 3) << 4) + (((hc >> 5) & 1) << 3) + (hc & 7);
}

// ---------------------------------------------------------------- fused prep
// [0,4096): cast x->xb bf16 ; [4096,8192): perm-cast W->Wbp bf16 (row 4h+g);
// [8192,9216): U -> Up8 fp8-image (row 4h+g, scale 32) ; [9216,9232): bp.
__global__ __launch_bounds__(256) void prep_kernel(
    const float* __restrict__ x, const float* __restrict__ W,
    const float* __restrict__ U, const float* __restrict__ bW,
    const float* __restrict__ bU, unsigned short* __restrict__ xb,
    unsigned short* __restrict__ Wbp, unsigned char* __restrict__ Up8,
    float* __restrict__ bp) {
  const int bid = blockIdx.x;
  if (bid < 4096) {
    const int i = bid * 256 + threadIdx.x;
    const float4 v = reinterpret_cast<const float4*>(x)[i];
    ushort4 o;
    o.x = f2b(v.x); o.y = f2b(v.y); o.z = f2b(v.z); o.w = f2b(v.w);
    reinterpret_cast<ushort4*>(xb)[i] = o;
  } else if (bid < 8192) {
    const int i = (bid - 4096) * 256 + threadIdx.x;
    const int r = i >> 8;
    const int cw = i & 255;
    const float4 v = reinterpret_cast<const float4*>(W)[i];
    const int rp = ((r & 1023) << 2) + (r >> 10);  // 4h+g
    ushort4 o;
    o.x = f2b(v.x); o.y = f2b(v.y); o.z = f2b(v.z); o.w = f2b(v.w);
    *reinterpret_cast<ushort4*>(&Wbp[(size_t)rp * 1024 + (cw << 2)]) = o;
  } else if (bid < 9216) {
    // U fp8 image: dest granule d0 = 16 bytes; rp = dest row (4h+g)
    const int i = (bid - 8192) * 256 + threadIdx.x;  // 0..262143
    const int d0 = i << 4;
    const int rp = d0 >> 10;
    const int ik0 = d0 & 1023;
    const int P = ik0 >> 6, q = (ik0 >> 4) & 3;
    const int k0 = P * 64 + q * 8;
    const int srcrow = (rp & 3) * 1024 + (rp >> 2);  // g*1024 + h
    const float* S = U + (size_t)srcrow * 1024;
    const float4 a0 = *reinterpret_cast<const float4*>(S + k0);
    const float4 a1 = *reinterpret_cast<const float4*>(S + k0 + 4);
    const float4 b0 = *reinterpret_cast<const float4*>(S + k0 + 32);
    const float4 b1 = *reinterpret_cast<const float4*>(S + k0 + 36);
    auto pk = [](unsigned char a, unsigned char b, unsigned char c, unsigned char d) {
      return (unsigned)a | ((unsigned)b << 8) | ((unsigned)c << 16) | ((unsigned)d << 24);
    };
    uint4 w;
    w.x = pk(f2fp8(a0.x * 32.f), f2fp8(a0.y * 32.f), f2fp8(a0.z * 32.f), f2fp8(a0.w * 32.f));
    w.y = pk(f2fp8(a1.x * 32.f), f2fp8(a1.y * 32.f), f2fp8(a1.z * 32.f), f2fp8(a1.w * 32.f));
    w.z = pk(f2fp8(b0.x * 32.f), f2fp8(b0.y * 32.f), f2fp8(b0.z * 32.f), f2fp8(b0.w * 32.f));
    w.w = pk(f2fp8(b1.x * 32.f), f2fp8(b1.y * 32.f), f2fp8(b1.z * 32.f), f2fp8(b1.w * 32.f));
    *reinterpret_cast<uint4*>(&Up8[d0]) = w;
  } else {
    const int i = (bid - 9216) * 256 + threadIdx.x;  // 0..4095
    const int h = i >> 2, g = i & 3;
    bp[i] = bW[g * 1024 + h] + bU[g * 1024 + h];
  }
}

// ============================ bf16 GEMM (t=0) — R11-verified K-loop ==========
#define KPHASE(BFC, BFN, SLNXT, STAGEQ, DOSTAGE, WAITSTR, DOBAR)              \
  {                                                                           \
    if (DOSTAGE) STAGE(STAGEQ);                                               \
    const unsigned char* sln_ = (SLNXT);                                      \
    _Pragma("unroll") for (int n_ = 0; n_ < 4; ++n_)                          \
        BFN[n_] = *reinterpret_cast<const bf16x8*>(sln_ + offB[n_]);          \
    __builtin_amdgcn_s_setprio(1);                                            \
    _Pragma("unroll") for (int m_ = 0; m_ < 8; ++m_) {                        \
      _Pragma("unroll") for (int n_ = 0; n_ < 4; ++n_)                        \
          acc[m_][n_] = __builtin_amdgcn_mfma_f32_16x16x32_bf16(              \
              af[m_], BFC[n_], acc[m_][n_], 0, 0, 0);                         \
      af[m_] = *reinterpret_cast<const bf16x8*>(sln_ + offA[m_]);             \
    }                                                                         \
    __builtin_amdgcn_s_setprio(0);                                            \
    asm volatile(WAITSTR ::: "memory");                                       \
    __builtin_amdgcn_sched_barrier(0);                                        \
    if (DOBAR) {                                                              \
      __builtin_amdgcn_s_barrier();                                           \
      __builtin_amdgcn_sched_barrier(0);                                      \
    }                                                                         \
  }

// x-projection GEMM + fused first-step gates (c0=0): writes xpb (proj+bias,
// bf16), ct (bf16), ht -> fp8 image (scale 16).
__global__ __launch_bounds__(512, 2) void gemm_x(
    const unsigned short* __restrict__ A,    // xb bf16 [4096,1024]
    const unsigned short* __restrict__ Bm,   // Wbp bf16 [4096,1024]
    unsigned short* __restrict__ xpb_w,      // [B,4H] bf16
    const float* __restrict__ bp,            // [4H]
    unsigned short* __restrict__ ct,         // [B,H] bf16
    unsigned char* __restrict__ htimg) {     // [B,1024] fp8 image
  constexpr int K = 1024, N = 4096;
  constexpr int NPH = K / 32;
  __shared__ unsigned char lds[256 * 528];

  const int tid = threadIdx.x;
  const int lane = tid & 63;
  const int wave = tid >> 6;
  const int wr = wave >> 2, wc = wave & 3;
  const int bid = blockIdx.x;
  const int sw = (bid & 7) * 32 + (bid >> 3);
  const int brow = (sw >> 4) * 256, bcol = (sw & 15) * 256;

  const int physA0 = tid * 16, physA1 = 8192 + tid * 16;
  const int physB0 = 16384 + tid * 16, physB1 = 24576 + tid * 16;
  const int LA0 = swz(physA0), LA1 = swz(physA1 - 8192) + 0;  // note: within-region
  const int LA1r = swz(8192 + tid * 16);  // rows 128-255 region offset (R11 form)
  const int LB0 = swz(tid * 16), LB1 = swz(8192 + tid * 16);
  const unsigned char* pA0 = (const unsigned char*)A + (size_t)(brow + (LA0 >> 6)) * (K * 2) + (LA0 & 63);
  const unsigned char* pA1 = (const unsigned char*)A + (size_t)(brow + (LA1r >> 6)) * (K * 2) + (LA1r & 63);
  const unsigned char* pB0 = (const unsigned char*)Bm + (size_t)(bcol + (LB0 >> 6)) * (K * 2) + (LB0 & 63);
  const unsigned char* pB1 = (const unsigned char*)Bm + (size_t)(bcol + (LB1 >> 6)) * (K * 2) + (LB1 & 63);

  const int s16 = (lane >> 4) * 16;
  int offA[8], offB[4];
#pragma unroll
  for (int m = 0; m < 8; ++m)
    offA[m] = swz((wr * 128 + m * 16 + (lane & 15)) * 64 + s16);
#pragma unroll
  for (int n = 0; n < 4; ++n)
    offB[n] = 16384 + swz((wc * 64 + n * 16 + (lane & 15)) * 64 + s16);

  f32x4 acc[8][4] = {};
  bf16x8 af[8], bfE[4], bfO[4];

  auto STAGE = [&](int q) {
    unsigned char* sb = lds + (q & 3) * 32768;
    const size_t kb = (size_t)q * 64;
    load_lds16(pA0 + kb, sb + physA0);
    load_lds16(pA1 + kb, sb + physA1);
    load_lds16(pB0 + kb, sb + physB0);
    load_lds16(pB1 + kb, sb + physB1);
  };

  STAGE(0); STAGE(1); STAGE(2); STAGE(3);
  asm volatile("s_waitcnt vmcnt(8)" ::: "memory");
  __builtin_amdgcn_s_barrier();
#pragma unroll
  for (int n = 0; n < 4; ++n) bfE[n] = *reinterpret_cast<const bf16x8*>(lds + offB[n]);
#pragma unroll
  for (int m = 0; m < 8; ++m) af[m] = *reinterpret_cast<const bf16x8*>(lds + offA[m]);
  asm volatile("s_waitcnt lgkmcnt(0)" ::: "memory");
  __builtin_amdgcn_sched_barrier(0);
  __builtin_amdgcn_s_barrier();
  __builtin_amdgcn_sched_barrier(0);

  for (int pp = 0; pp < 14; ++pp) {
    const int p = 2 * pp;
    const unsigned char* sl1 = lds + ((p + 1) & 3) * 32768;
    const unsigned char* sl2 = lds + ((p + 2) & 3) * 32768;
    KPHASE(bfE, bfO, sl1, p + 4, true, "s_waitcnt vmcnt(8) lgkmcnt(0)", true);
    KPHASE(bfO, bfE, sl2, p + 5, true, "s_waitcnt vmcnt(8) lgkmcnt(0)", true);
  }
  KPHASE(bfE, bfO, lds + (29 & 3) * 32768, 0, false, "s_waitcnt vmcnt(4) lgkmcnt(0)", true);
  KPHASE(bfO, bfE, lds + (30 & 3) * 32768, 0, false, "s_waitcnt vmcnt(0) lgkmcnt(0)", true);
  KPHASE(bfE, bfO, lds + (31 & 3) * 32768, 0, false, "s_waitcnt lgkmcnt(0)", false);
  __builtin_amdgcn_s_setprio(1);
#pragma unroll
  for (int m = 0; m < 8; ++m)
#pragma unroll
    for (int n = 0; n < 4; ++n)
      acc[m][n] = __builtin_amdgcn_mfma_f32_16x16x32_bf16(af[m], bfO[n], acc[m][n], 0, 0, 0);
  __builtin_amdgcn_s_setprio(0);

  __syncthreads();
  unsigned short* cs = (unsigned short*)lds;
  {
    const int c0 = wc * 64 + (lane & 15);
    const int r00 = wr * 128 + ((lane >> 4) << 2);
#pragma unroll
    for (int m = 0; m < 8; ++m)
#pragma unroll
      for (int n = 0; n < 4; ++n) {
        const int rr = r00 + m * 16, cc = c0 + n * 16;
#pragma unroll
        for (int r = 0; r < 4; ++r) cs[(rr + r) * 264 + cc] = f2b(acc[m][n][r]);
      }
  }
  __syncthreads();

  const int hbase = bcol >> 2;
#pragma unroll 2
  for (int j = 0; j < 8; ++j) {
    const int v = tid + (j << 9);
    const int row = v >> 4;
    const int h4 = (v & 15) << 2;
    const int ci = (brow + row) * 1024 + hbase + h4;

    unsigned short pvv[16];
    *reinterpret_cast<uint4*>(&pvv[0]) = *reinterpret_cast<const uint4*>(&cs[row * 264 + h4 * 4]);
    *reinterpret_cast<uint4*>(&pvv[8]) = *reinterpret_cast<const uint4*>(&cs[row * 264 + h4 * 4 + 8]);

    float bpf[16];
#pragma unroll
    for (int q = 0; q < 4; ++q)
      *reinterpret_cast<float4*>(&bpf[q * 4]) =
          *reinterpret_cast<const float4*>(&bp[bcol + h4 * 4 + q * 4]);

    float sf[4], si_[4], so_[4], sg_[4];
    unsigned short xo[16];
#pragma unroll
    for (int k = 0; k < 4; ++k) {
      sf[k] = b2f(pvv[4 * k + 0]) + bpf[4 * k + 0];
      si_[k] = b2f(pvv[4 * k + 1]) + bpf[4 * k + 1];
      so_[k] = b2f(pvv[4 * k + 2]) + bpf[4 * k + 2];
      sg_[k] = b2f(pvv[4 * k + 3]) + bpf[4 * k + 3];
      xo[4 * k + 0] = f2b(sf[k]);
      xo[4 * k + 1] = f2b(si_[k]);
      xo[4 * k + 2] = f2b(so_[k]);
      xo[4 * k + 3] = f2b(sg_[k]);
    }
    unsigned short* xw = &xpb_w[(size_t)(brow + row) * N + bcol + h4 * 4];
    *reinterpret_cast<uint4*>(xw) = *reinterpret_cast<const uint4*>(&xo[0]);
    *reinterpret_cast<uint4*>(xw + 8) = *reinterpret_cast<const uint4*>(&xo[8]);

    float cn[4], hn[4];
#pragma unroll
    for (int k = 0; k < 4; ++k) {
      const float ii = sigm(si_[k]);
      const float o = sigm(so_[k]);
      const float gg = tanh_fast(sg_[k]);
      const float c = ii * gg;  // f*0 + i*g
      cn[k] = c;
      hn[k] = o * tanh_fast(c);
    }
    ushort4 cb;
    cb.x = f2b(cn[0]); cb.y = f2b(cn[1]); cb.z = f2b(cn[2]); cb.w = f2b(cn[3]);
    *reinterpret_cast<ushort4*>(&ct[ci]) = cb;
    const int hc0 = hbase + h4;
    uchar4 h8;
    h8.x = f2fp8(hn[0] * 16.f); h8.y = f2fp8(hn[1] * 16.f);
    h8.z = f2fp8(hn[2] * 16.f); h8.w = f2fp8(hn[3] * 16.f);
    *reinterpret_cast<uchar4*>(&htimg[(size_t)(brow + row) * 1024 + imgk(hc0)]) = h8;
  }
}

// ============================ fp8 GEMM (t=1..7) ==============================
// A,B are fp8 images: [row][64B rows], per 16B granule = [tileA 8B | tileB 8B].
// One b128 read = MFMA operands for TWO k-tiles -> 16 phases of K=64.
// R9-verified 4-slot / counted-vmcnt(8) ledger and swizzle, byte-identical.
#define KPHASE8(BFC, BFN, SLNXT, STAGEQ, DOSTAGE, WAITSTR, DOBAR)             \
  {                                                                           \
    if (DOSTAGE) STAGE(STAGEQ);                                               \
    const unsigned char* sln_ = (SLNXT);                                      \
    _Pragma("unroll") for (int n_ = 0; n_ < 4; ++n_)                          \
        BFN[n_] = *reinterpret_cast<const i64x2*>(sln_ + offB[n_]);           \
    __builtin_amdgcn_s_setprio(1);                                            \
    _Pragma("unroll") for (int m_ = 0; m_ < 8; ++m_) {                        \
      _Pragma("unroll") for (int n_ = 0; n_ < 4; ++n_)                        \
          acc[m_][n_] = __builtin_amdgcn_mfma_f32_16x16x32_fp8_fp8(           \
              af[m_][0], BFC[n_][0], acc[m_][n_], 0, 0, 0);                   \
      _Pragma("unroll") for (int n_ = 0; n_ < 4; ++n_)                        \
          acc[m_][n_] = __builtin_amdgcn_mfma_f32_16x16x32_fp8_fp8(           \
              af[m_][1], BFC[n_][1], acc[m_][n_], 0, 0, 0);                   \
      af[m_] = *reinterpret_cast<const i64x2*>(sln_ + offA[m_]);              \
    }                                                                         \
    __builtin_amdgcn_s_setprio(0);                                            \
    asm volatile(WAITSTR ::: "memory");                                       \
    __builtin_amdgcn_sched_barrier(0);                                        \
    if (DOBAR) {                                                              \
      __builtin_amdgcn_s_barrier();                                           \
      __builtin_amdgcn_sched_barrier(0);                                      \
    }                                                                         \
  }

template <bool LAST>
__global__ __launch_bounds__(512, 2) void gemm_r(
    const unsigned char* __restrict__ Aimg,  // ht fp8 image [4096][1024]
    const unsigned char* __restrict__ Bimg,  // Up8 image [4096][1024]
    const unsigned short* __restrict__ xpb_r,
    unsigned short* __restrict__ ct,
    unsigned char* __restrict__ htimg,       // next-step A image
    float* __restrict__ out) {
  constexpr int N = 4096;
  constexpr int NPH = 16;  // 16 phases x K=64
  __shared__ unsigned char lds[256 * 528];  // 4 slots x 32KB + epilogue cs

  const int tid = threadIdx.x;
  const int lane = tid & 63;
  const int wave = tid >> 6;
  const int wr = wave >> 2, wc = wave & 3;
  const int bid = blockIdx.x;
  const int sw = (bid & 7) * 32 + (bid >> 3);
  const int brow = (sw >> 4) * 256, bcol = (sw & 15) * 256;

  const int physA0 = tid * 16, physA1 = 8192 + tid * 16;
  const int physB0 = 16384 + tid * 16, physB1 = 24576 + tid * 16;
  const int LA0 = swz(tid * 16), LA1 = swz(8192 + tid * 16);
  const unsigned char* pA0 = Aimg + (size_t)(brow + (LA0 >> 6)) * 1024 + (LA0 & 63);
  const unsigned char* pA1 = Aimg + (size_t)(brow + (LA1 >> 6)) * 1024 + (LA1 & 63);
  const unsigned char* pB0 = Bimg + (size_t)(bcol + (LA0 >> 6)) * 1024 + (LA0 & 63);
  const unsigned char* pB1 = Bimg + (size_t)(bcol + (LA1 >> 6)) * 1024 + (LA1 & 63);

  const int s16 = (lane >> 4) * 16;
  int offA[8], offB[4];
#pragma unroll
  for (int m = 0; m < 8; ++m)
    offA[m] = swz((wr * 128 + m * 16 + (lane & 15)) * 64 + s16);
#pragma unroll
  for (int n = 0; n < 4; ++n)
    offB[n] = 16384 + swz((wc * 64 + n * 16 + (lane & 15)) * 64 + s16);

  f32x4 acc[8][4] = {};
  i64x2 af[8], bfE[4], bfO[4];

  auto STAGE = [&](int q) {
    unsigned char* sb = lds + (q & 3) * 32768;
    const size_t kb = (size_t)q * 64;
    load_lds16(pA0 + kb, sb + physA0);
    load_lds16(pA1 + kb, sb + physA1);
    load_lds16(pB0 + kb, sb + physB0);
    load_lds16(pB1 + kb, sb + physB1);
  };

  STAGE(0); STAGE(1); STAGE(2); STAGE(3);
  asm volatile("s_waitcnt vmcnt(8)" ::: "memory");
  __builtin_amdgcn_s_barrier();
#pragma unroll
  for (int n = 0; n < 4; ++n) bfE[n] = *reinterpret_cast<const i64x2*>(lds + offB[n]);
#pragma unroll
  for (int m = 0; m < 8; ++m) af[m] = *reinterpret_cast<const i64x2*>(lds + offA[m]);
  asm volatile("s_waitcnt lgkmcnt(0)" ::: "memory");
  __builtin_amdgcn_sched_barrier(0);
  __builtin_amdgcn_s_barrier();
  __builtin_amdgcn_sched_barrier(0);

  // phases 0..11 uniform: stage p+4, counted vmcnt(8)
  for (int pp = 0; pp < 6; ++pp) {
    const int p = 2 * pp;
    const unsigned char* sl1 = lds + ((p + 1) & 3) * 32768;
    const unsigned char* sl2 = lds + ((p + 2) & 3) * 32768;
    KPHASE8(bfE, bfO, sl1, p + 4, true, "s_waitcnt vmcnt(8) lgkmcnt(0)", true);
    KPHASE8(bfO, bfE, sl2, p + 5, true, "s_waitcnt vmcnt(8) lgkmcnt(0)", true);
  }
  // p=12: retire slot 14 -> vmcnt(4); p=13: retire 15 -> vmcnt(0); p=14: lgkm only
  KPHASE8(bfE, bfO, lds + (13 & 3) * 32768, 0, false, "s_waitcnt vmcnt(4) lgkmcnt(0)", true);
  KPHASE8(bfO, bfE, lds + (14 & 3) * 32768, 0, false, "s_waitcnt vmcnt(0) lgkmcnt(0)", true);
  KPHASE8(bfE, bfO, lds + (15 & 3) * 32768, 0, false, "s_waitcnt lgkmcnt(0)", false);
  // p=15: MFMA only
  __builtin_amdgcn_s_setprio(1);
#pragma unroll
  for (int m = 0; m < 8; ++m) {
#pragma unroll
    for (int n = 0; n < 4; ++n)
      acc[m][n] = __builtin_amdgcn_mfma_f32_16x16x32_fp8_fp8(af[m][0], bfO[n][0], acc[m][n], 0, 0, 0);
#pragma unroll
    for (int n = 0; n < 4; ++n)
      acc[m][n] = __builtin_amdgcn_mfma_f32_16x16x32_fp8_fp8(af[m][1], bfO[n][1], acc[m][n], 0, 0, 0);
  }
  __builtin_amdgcn_s_setprio(0);

  // ---- epilogue: proj = acc/512 (undo U*32 * h*16 scaling)
  __syncthreads();
  unsigned short* cs = (unsigned short*)lds;
  {
    const float inv = 1.0f / 512.0f;
    const int c0 = wc * 64 + (lane & 15);
    const int r00 = wr * 128 + ((lane >> 4) << 2);
#pragma unroll
    for (int m = 0; m < 8; ++m)
#pragma unroll
      for (int n = 0; n < 4; ++n) {
        const int rr = r00 + m * 16, cc = c0 + n * 16;
#pragma unroll
        for (int r = 0; r < 4; ++r) cs[(rr + r) * 264 + cc] = f2b(acc[m][n][r] * inv);
      }
  }
  __syncthreads();

  const int hbase = bcol >> 2;
#pragma unroll 2
  for (int j = 0; j < 8; ++j) {
    const int v = tid + (j << 9);
    const int row = v >> 4;
    const int h4 = (v & 15) << 2;
    const int ci = (brow + row) * 1024 + hbase + h4;

    unsigned short pvv[16], xvv[16];
    *reinterpret_cast<uint4*>(&pvv[0]) = *reinterpret_cast<const uint4*>(&cs[row * 264 + h4 * 4]);
    *reinterpret_cast<uint4*>(&pvv[8]) = *reinterpret_cast<const uint4*>(&cs[row * 264 + h4 * 4 + 8]);
    const unsigned short* xr = &xpb_r[(size_t)(brow + row) * N + bcol + h4 * 4];
    *reinterpret_cast<uint4*>(&xvv[0]) = *reinterpret_cast<const uint4*>(xr);
    *reinterpret_cast<uint4*>(&xvv[8]) = *reinterpret_cast<const uint4*>(xr + 8);

    const ushort4 cv = *reinterpret_cast<const ushort4*>(&ct[ci]);
    float c_old[4] = {b2f(cv.x), b2f(cv.y), b2f(cv.z), b2f(cv.w)};

    float cn[4], hn[4];
#pragma unroll
    for (int k = 0; k < 4; ++k) {
      const float f = sigm(b2f(pvv[4 * k + 0]) + b2f(xvv[4 * k + 0]));
      const float ii = sigm(b2f(pvv[4 * k + 1]) + b2f(xvv[4 * k + 1]));
      const float o = sigm(b2f(pvv[4 * k + 2]) + b2f(xvv[4 * k + 2]));
      const float gg = tanh_fast(b2f(pvv[4 * k + 3]) + b2f(xvv[4 * k + 3]));
      const float c = fmaf(f, c_old[k], ii * gg);
      cn[k] = c;
      hn[k] = o * tanh_fast(c);
    }

    if constexpr (LAST) {
      *reinterpret_cast<float4*>(&out[ci]) = make_float4(hn[0], hn[1], hn[2], hn[3]);
      *reinterpret_cast<float4*>(&out[4194304 + ci]) = make_float4(cn[0], cn[1], cn[2], cn[3]);
    } else {
      ushort4 cb;
      cb.x = f2b(cn[0]); cb.y = f2b(cn[1]); cb.z = f2b(cn[2]); cb.w = f2b(cn[3]);
      *reinterpret_cast<ushort4*>(&ct[ci]) = cb;
      const int hc0 = hbase + h4;
      uchar4 h8;
      h8.x = f2fp8(hn[0] * 16.f); h8.y = f2fp8(hn[1] * 16.f);
      h8.z = f2fp8(hn[2] * 16.f); h8.w = f2fp8(hn[3] * 16.f);
      *reinterpret_cast<uchar4*>(&htimg[(size_t)(brow + row) * 1024 + imgk(hc0)]) = h8;
    }
  }
}

// ---------------------------------------------------------------- launch
extern "C" void kernel_launch(void* const* d_in, const int* in_sizes, int n_in,
                              void* d_out, int out_size, void* d_ws, size_t ws_size,
                              hipStream_t stream) {
  const float* x = (const float*)d_in[0];
  const float* W = (const float*)d_in[1];
  const float* bW = (const float*)d_in[2];
  const float* U = (const float*)d_in[3];
  const float* bU = (const float*)d_in[4];
  float* out = (float*)d_out;

  char* w = (char*)d_ws;
  const size_t MB = 1ull << 20;
  unsigned short* xb = (unsigned short*)(w + 0 * MB);    // 8 MB bf16
  unsigned short* Wbp = (unsigned short*)(w + 8 * MB);   // 8 MB bf16 (gate-interleaved)
  unsigned char* Up8 = (unsigned char*)(w + 16 * MB);    // 4 MB fp8 image (x32)
  unsigned short* xpb = (unsigned short*)(w + 24 * MB);  // 32 MB bf16 proj+bias
  unsigned short* ct = (unsigned short*)(w + 56 * MB);   // 8 MB bf16 state
  unsigned char* htA = (unsigned char*)(w + 64 * MB);    // 4 MB fp8 image (x16)
  unsigned char* htB = (unsigned char*)(w + 68 * MB);    // 4 MB fp8 image
  float* bp = (float*)(w + 72 * MB);                     // 16 KB

  prep_kernel<<<9232, 256, 0, stream>>>(x, W, U, bW, bU, xb, Wbp, Up8, bp);

  // t=0: bf16 x-projection + fused gates (c0=0): writes xpb, ct, htA(fp8 img)
  gemm_x<<<256, 512, 0, stream>>>(xb, Wbp, xpb, bp, ct, htA);

  const unsigned char* hin = htA;
  unsigned char* hout = htB;
  for (int t = 1; t <= 6; ++t) {
    gemm_r<false><<<256, 512, 0, stream>>>(hin, Up8, xpb, ct, hout, nullptr);
    const unsigned char* tmp = hout;
    hout = (unsigned char*)hin;
    hin = tmp;
  }
  gemm_r<true><<<256, 512, 0, stream>>>(hin, Up8, xpb, ct, nullptr, out);
}

// Round 13
// 350.204 us; speedup vs baseline: 1.1937x; 1.0289x over previous
//
#include <hip/hip_runtime.h>
#include <hip/hip_bf16.h>

typedef __bf16 bf16x8 __attribute__((ext_vector_type(8)));
typedef float f32x4 __attribute__((ext_vector_type(4)));
typedef long i64x2 __attribute__((ext_vector_type(2)));

#define DEVI static __device__ __forceinline__

DEVI void load_lds16(const void* g, void* l) {
  __builtin_amdgcn_global_load_lds(
      (const __attribute__((address_space(1))) void*)g,
      (__attribute__((address_space(3))) void*)l, 16, 0, 0);
}

DEVI unsigned short f2b(float f) { return __bfloat16_as_ushort(__float2bfloat16(f)); }
DEVI float b2f(unsigned short u) {
  union { unsigned int i; float f; } c;
  c.i = ((unsigned int)u) << 16;
  return c.f;
}
DEVI float sigm(float x) { return 1.0f / (1.0f + __expf(-x)); }
DEVI float tanh_fast(float x) { return 2.0f / (1.0f + __expf(-2.0f * x)) - 1.0f; }

// float -> OCP e4m3fn with RNE (hand-rolled; sat to 448, subnormals handled)
DEVI unsigned char f2fp8(float f) {
  const unsigned int u = __float_as_uint(f);
  const unsigned char s = (unsigned char)((u >> 24) & 0x80);
  const float a = fabsf(f);
  if (a >= 448.f) return s | 0x7E;
  if (a < 0.015625f) {  // subnormal range: value = M * 2^-9
    const int M = (int)rintf(a * 512.f);
    if (M > 7) return s | 0x08;
    return s | (unsigned char)M;
  }
  int ex;
  const float m = frexpf(a, &ex);
  int r = (int)rintf(m * 16.f);
  if (r == 16) { r = 8; ex += 1; }
  const int E = ex + 6, M = r - 8;
  if (E > 15 || (E == 15 && M == 7)) return s | 0x7E;
  return s | (unsigned char)((E << 3) | M);
}

// involutive 16B-granule swizzle (64B rows): XOR byte-bits 4-6 with bits 7-9.
// Verified conflict-free for the 16-row fragment/staging patterns (R3-R12).
DEVI int swz(int L) { return L ^ (((L >> 7) & 7) << 4); }

// fp8 image k-index: true col hc -> image byte (pair-tile interleave along K).
DEVI int imgk(int hc) {
  return (hc & ~63) + (((hc >> 3) & 3) << 4) + (((hc >> 5) & 1) << 3) + (hc & 7);
}

// ---------------------------------------------------------------- fused prep (R12-verified)
__global__ __launch_bounds__(256) void prep_kernel(
    const float* __restrict__ x, const float* __restrict__ W,
    const float* __restrict__ U, const float* __restrict__ bW,
    const float* __restrict__ bU, unsigned short* __restrict__ xb,
    unsigned short* __restrict__ Wbp, unsigned char* __restrict__ Up8,
    float* __restrict__ bp) {
  const int bid = blockIdx.x;
  if (bid < 4096) {
    const int i = bid * 256 + threadIdx.x;
    const float4 v = reinterpret_cast<const float4*>(x)[i];
    ushort4 o;
    o.x = f2b(v.x); o.y = f2b(v.y); o.z = f2b(v.z); o.w = f2b(v.w);
    reinterpret_cast<ushort4*>(xb)[i] = o;
  } else if (bid < 8192) {
    const int i = (bid - 4096) * 256 + threadIdx.x;
    const int r = i >> 8;
    const int cw = i & 255;
    const float4 v = reinterpret_cast<const float4*>(W)[i];
    const int rp = ((r & 1023) << 2) + (r >> 10);  // 4h+g
    ushort4 o;
    o.x = f2b(v.x); o.y = f2b(v.y); o.z = f2b(v.z); o.w = f2b(v.w);
    *reinterpret_cast<ushort4*>(&Wbp[(size_t)rp * 1024 + (cw << 2)]) = o;
  } else if (bid < 9216) {
    const int i = (bid - 8192) * 256 + threadIdx.x;
    const int d0 = i << 4;
    const int rp = d0 >> 10;
    const int ik0 = d0 & 1023;
    const int P = ik0 >> 6, q = (ik0 >> 4) & 3;
    const int k0 = P * 64 + q * 8;
    const int srcrow = (rp & 3) * 1024 + (rp >> 2);  // g*1024 + h
    const float* S = U + (size_t)srcrow * 1024;
    const float4 a0 = *reinterpret_cast<const float4*>(S + k0);
    const float4 a1 = *reinterpret_cast<const float4*>(S + k0 + 4);
    const float4 b0 = *reinterpret_cast<const float4*>(S + k0 + 32);
    const float4 b1 = *reinterpret_cast<const float4*>(S + k0 + 36);
    auto pk = [](unsigned char a, unsigned char b, unsigned char c, unsigned char d) {
      return (unsigned)a | ((unsigned)b << 8) | ((unsigned)c << 16) | ((unsigned)d << 24);
    };
    uint4 w;
    w.x = pk(f2fp8(a0.x * 32.f), f2fp8(a0.y * 32.f), f2fp8(a0.z * 32.f), f2fp8(a0.w * 32.f));
    w.y = pk(f2fp8(a1.x * 32.f), f2fp8(a1.y * 32.f), f2fp8(a1.z * 32.f), f2fp8(a1.w * 32.f));
    w.z = pk(f2fp8(b0.x * 32.f), f2fp8(b0.y * 32.f), f2fp8(b0.z * 32.f), f2fp8(b0.w * 32.f));
    w.w = pk(f2fp8(b1.x * 32.f), f2fp8(b1.y * 32.f), f2fp8(b1.z * 32.f), f2fp8(b1.w * 32.f));
    *reinterpret_cast<uint4*>(&Up8[d0]) = w;
  } else {
    const int i = (bid - 9216) * 256 + threadIdx.x;
    const int h = i >> 2, g = i & 3;
    bp[i] = bW[g * 1024 + h] + bU[g * 1024 + h];
  }
}

// ============================ bf16 GEMM (t=0) — R12-verified =================
#define KPHASE(BFC, BFN, SLNXT, STAGEQ, DOSTAGE, WAITSTR, DOBAR)              \
  {                                                                           \
    if (DOSTAGE) STAGE(STAGEQ);                                               \
    const unsigned char* sln_ = (SLNXT);                                      \
    _Pragma("unroll") for (int n_ = 0; n_ < 4; ++n_)                          \
        BFN[n_] = *reinterpret_cast<const bf16x8*>(sln_ + offB[n_]);          \
    __builtin_amdgcn_s_setprio(1);                                            \
    _Pragma("unroll") for (int m_ = 0; m_ < 8; ++m_) {                        \
      _Pragma("unroll") for (int n_ = 0; n_ < 4; ++n_)                        \
          acc[m_][n_] = __builtin_amdgcn_mfma_f32_16x16x32_bf16(              \
              af[m_], BFC[n_], acc[m_][n_], 0, 0, 0);                         \
      af[m_] = *reinterpret_cast<const bf16x8*>(sln_ + offA[m_]);             \
    }                                                                         \
    __builtin_amdgcn_s_setprio(0);                                            \
    asm volatile(WAITSTR ::: "memory");                                       \
    __builtin_amdgcn_sched_barrier(0);                                        \
    if (DOBAR) {                                                              \
      __builtin_amdgcn_s_barrier();                                           \
      __builtin_amdgcn_sched_barrier(0);                                      \
    }                                                                         \
  }

__global__ __launch_bounds__(512, 2) void gemm_x(
    const unsigned short* __restrict__ A,
    const unsigned short* __restrict__ Bm,
    unsigned short* __restrict__ xpb_w,
    const float* __restrict__ bp,
    unsigned short* __restrict__ ct,
    unsigned char* __restrict__ htimg) {
  constexpr int K = 1024, N = 4096;
  __shared__ unsigned char lds[256 * 528];

  const int tid = threadIdx.x;
  const int lane = tid & 63;
  const int wave = tid >> 6;
  const int wr = wave >> 2, wc = wave & 3;
  const int bid = blockIdx.x;
  const int sw = (bid & 7) * 32 + (bid >> 3);
  const int brow = (sw >> 4) * 256, bcol = (sw & 15) * 256;

  const int physA0 = tid * 16, physA1 = 8192 + tid * 16;
  const int physB0 = 16384 + tid * 16, physB1 = 24576 + tid * 16;
  const int LA0 = swz(physA0);
  const int LA1r = swz(8192 + tid * 16);
  const int LB0 = swz(tid * 16), LB1 = swz(8192 + tid * 16);
  const unsigned char* pA0 = (const unsigned char*)A + (size_t)(brow + (LA0 >> 6)) * (K * 2) + (LA0 & 63);
  const unsigned char* pA1 = (const unsigned char*)A + (size_t)(brow + (LA1r >> 6)) * (K * 2) + (LA1r & 63);
  const unsigned char* pB0 = (const unsigned char*)Bm + (size_t)(bcol + (LB0 >> 6)) * (K * 2) + (LB0 & 63);
  const unsigned char* pB1 = (const unsigned char*)Bm + (size_t)(bcol + (LB1 >> 6)) * (K * 2) + (LB1 & 63);

  const int s16 = (lane >> 4) * 16;
  int offA[8], offB[4];
#pragma unroll
  for (int m = 0; m < 8; ++m)
    offA[m] = swz((wr * 128 + m * 16 + (lane & 15)) * 64 + s16);
#pragma unroll
  for (int n = 0; n < 4; ++n)
    offB[n] = 16384 + swz((wc * 64 + n * 16 + (lane & 15)) * 64 + s16);

  f32x4 acc[8][4] = {};
  bf16x8 af[8], bfE[4], bfO[4];

  auto STAGE = [&](int q) {
    unsigned char* sb = lds + (q & 3) * 32768;
    const size_t kb = (size_t)q * 64;
    load_lds16(pA0 + kb, sb + physA0);
    load_lds16(pA1 + kb, sb + physA1);
    load_lds16(pB0 + kb, sb + physB0);
    load_lds16(pB1 + kb, sb + physB1);
  };

  STAGE(0); STAGE(1); STAGE(2); STAGE(3);
  asm volatile("s_waitcnt vmcnt(8)" ::: "memory");
  __builtin_amdgcn_s_barrier();
#pragma unroll
  for (int n = 0; n < 4; ++n) bfE[n] = *reinterpret_cast<const bf16x8*>(lds + offB[n]);
#pragma unroll
  for (int m = 0; m < 8; ++m) af[m] = *reinterpret_cast<const bf16x8*>(lds + offA[m]);
  asm volatile("s_waitcnt lgkmcnt(0)" ::: "memory");
  __builtin_amdgcn_sched_barrier(0);
  __builtin_amdgcn_s_barrier();
  __builtin_amdgcn_sched_barrier(0);

  for (int pp = 0; pp < 14; ++pp) {
    const int p = 2 * pp;
    const unsigned char* sl1 = lds + ((p + 1) & 3) * 32768;
    const unsigned char* sl2 = lds + ((p + 2) & 3) * 32768;
    KPHASE(bfE, bfO, sl1, p + 4, true, "s_waitcnt vmcnt(8) lgkmcnt(0)", true);
    KPHASE(bfO, bfE, sl2, p + 5, true, "s_waitcnt vmcnt(8) lgkmcnt(0)", true);
  }
  KPHASE(bfE, bfO, lds + (29 & 3) * 32768, 0, false, "s_waitcnt vmcnt(4) lgkmcnt(0)", true);
  KPHASE(bfO, bfE, lds + (30 & 3) * 32768, 0, false, "s_waitcnt vmcnt(0) lgkmcnt(0)", true);
  KPHASE(bfE, bfO, lds + (31 & 3) * 32768, 0, false, "s_waitcnt lgkmcnt(0)", false);
  __builtin_amdgcn_s_setprio(1);
#pragma unroll
  for (int m = 0; m < 8; ++m)
#pragma unroll
    for (int n = 0; n < 4; ++n)
      acc[m][n] = __builtin_amdgcn_mfma_f32_16x16x32_bf16(af[m], bfO[n], acc[m][n], 0, 0, 0);
  __builtin_amdgcn_s_setprio(0);

  __syncthreads();
  unsigned short* cs = (unsigned short*)lds;
  {
    const int c0 = wc * 64 + (lane & 15);
    const int r00 = wr * 128 + ((lane >> 4) << 2);
#pragma unroll
    for (int m = 0; m < 8; ++m)
#pragma unroll
      for (int n = 0; n < 4; ++n) {
        const int rr = r00 + m * 16, cc = c0 + n * 16;
#pragma unroll
        for (int r = 0; r < 4; ++r) cs[(rr + r) * 264 + cc] = f2b(acc[m][n][r]);
      }
  }
  __syncthreads();

  const int hbase = bcol >> 2;
#pragma unroll 2
  for (int j = 0; j < 8; ++j) {
    const int v = tid + (j << 9);
    const int row = v >> 4;
    const int h4 = (v & 15) << 2;
    const int ci = (brow + row) * 1024 + hbase + h4;

    unsigned short pvv[16];
    *reinterpret_cast<uint4*>(&pvv[0]) = *reinterpret_cast<const uint4*>(&cs[row * 264 + h4 * 4]);
    *reinterpret_cast<uint4*>(&pvv[8]) = *reinterpret_cast<const uint4*>(&cs[row * 264 + h4 * 4 + 8]);

    float bpf[16];
#pragma unroll
    for (int q = 0; q < 4; ++q)
      *reinterpret_cast<float4*>(&bpf[q * 4]) =
          *reinterpret_cast<const float4*>(&bp[bcol + h4 * 4 + q * 4]);

    float sf[4], si_[4], so_[4], sg_[4];
    unsigned short xo[16];
#pragma unroll
    for (int k = 0; k < 4; ++k) {
      sf[k] = b2f(pvv[4 * k + 0]) + bpf[4 * k + 0];
      si_[k] = b2f(pvv[4 * k + 1]) + bpf[4 * k + 1];
      so_[k] = b2f(pvv[4 * k + 2]) + bpf[4 * k + 2];
      sg_[k] = b2f(pvv[4 * k + 3]) + bpf[4 * k + 3];
      xo[4 * k + 0] = f2b(sf[k]);
      xo[4 * k + 1] = f2b(si_[k]);
      xo[4 * k + 2] = f2b(so_[k]);
      xo[4 * k + 3] = f2b(sg_[k]);
    }
    unsigned short* xw = &xpb_w[(size_t)(brow + row) * N + bcol + h4 * 4];
    *reinterpret_cast<uint4*>(xw) = *reinterpret_cast<const uint4*>(&xo[0]);
    *reinterpret_cast<uint4*>(xw + 8) = *reinterpret_cast<const uint4*>(&xo[8]);

    float cn[4], hn[4];
#pragma unroll
    for (int k = 0; k < 4; ++k) {
      const float ii = sigm(si_[k]);
      const float o = sigm(so_[k]);
      const float gg = tanh_fast(sg_[k]);
      const float c = ii * gg;
      cn[k] = c;
      hn[k] = o * tanh_fast(c);
    }
    ushort4 cb;
    cb.x = f2b(cn[0]); cb.y = f2b(cn[1]); cb.z = f2b(cn[2]); cb.w = f2b(cn[3]);
    *reinterpret_cast<ushort4*>(&ct[ci]) = cb;
    const int hc0 = hbase + h4;
    uchar4 h8;
    h8.x = f2fp8(hn[0] * 16.f); h8.y = f2fp8(hn[1] * 16.f);
    h8.z = f2fp8(hn[2] * 16.f); h8.w = f2fp8(hn[3] * 16.f);
    *reinterpret_cast<uchar4*>(&htimg[(size_t)(brow + row) * 1024 + imgk(hc0)]) = h8;
  }
}

// ============================ fp8 GEMM (t=1..7), high-occupancy ==============
// 128x128 tile, 4 waves (2x2), per-wave 64x64 -> acc 64 VGPR -> 3 waves/SIMD.
// 3 LDS slots x 16KB (A 8KB | B 8KB) = 48KB -> 3 blocks/CU. Reg-dbuf pipeline:
// phase p: MFMA(frags p, regs) || ds_read(frags p+1, slot (p+1)%3) ||
// STAGE(p+3 -> slot p%3, dead since barrier p-1->p). Per-wave ledger: 4
// loads/stage, 8 outstanding at boundary, vmcnt(4) retires stage(p+2); tail 4->0.
#define KPHASE8(BFC, BFN, SLNXT, STAGEQ, DOSTAGE, WAITSTR, DOBAR)             \
  {                                                                           \
    if (DOSTAGE) STAGE(STAGEQ);                                               \
    const unsigned char* sln_ = (SLNXT);                                      \
    _Pragma("unroll") for (int n_ = 0; n_ < 4; ++n_)                          \
        BFN[n_] = *reinterpret_cast<const i64x2*>(sln_ + offB[n_]);           \
    __builtin_amdgcn_s_setprio(1);                                            \
    _Pragma("unroll") for (int m_ = 0; m_ < 4; ++m_) {                        \
      _Pragma("unroll") for (int n_ = 0; n_ < 4; ++n_)                        \
          acc[m_][n_] = __builtin_amdgcn_mfma_f32_16x16x32_fp8_fp8(           \
              af[m_][0], BFC[n_][0], acc[m_][n_], 0, 0, 0);                   \
      _Pragma("unroll") for (int n_ = 0; n_ < 4; ++n_)                        \
          acc[m_][n_] = __builtin_amdgcn_mfma_f32_16x16x32_fp8_fp8(           \
              af[m_][1], BFC[n_][1], acc[m_][n_], 0, 0, 0);                   \
      af[m_] = *reinterpret_cast<const i64x2*>(sln_ + offA[m_]);              \
    }                                                                         \
    __builtin_amdgcn_s_setprio(0);                                            \
    asm volatile(WAITSTR ::: "memory");                                       \
    __builtin_amdgcn_sched_barrier(0);                                        \
    if (DOBAR) {                                                              \
      __builtin_amdgcn_s_barrier();                                           \
      __builtin_amdgcn_sched_barrier(0);                                      \
    }                                                                         \
  }

template <bool LAST>
__global__ __launch_bounds__(256, 3) void gemm_r(
    const unsigned char* __restrict__ Aimg,  // ht fp8 image [4096][1024]
    const unsigned char* __restrict__ Bimg,  // Up8 image [4096][1024]
    const unsigned short* __restrict__ xpb_r,
    unsigned short* __restrict__ ct,
    unsigned char* __restrict__ htimg,
    float* __restrict__ out) {
  constexpr int N = 4096;
  constexpr int SLOT = 16384;  // A [0,8192) 128r x 64B ; B [8192,16384)
  __shared__ unsigned char lds[3 * SLOT];  // 48KB; epilogue cs 128x132x2=33.8KB fits

  const int tid = threadIdx.x;
  const int lane = tid & 63;
  const int wave = tid >> 6;
  const int wr = wave >> 1, wc = wave & 1;  // 2x2 waves, per-wave 64x64
  const int bid = blockIdx.x;
  // XCD swizzle, nwg=1024 (32x32 tiles), divisible by 8
  const int sw = (bid & 7) * 128 + (bid >> 3);
  const int brow = (sw >> 5) * 128, bcol = (sw & 31) * 128;

  // staging: 4 x 16B loads/thread/slot (A:2, B:2), pre-swizzled global source
  const int physA0 = tid * 16, physA1 = 4096 + tid * 16;
  const int physB0 = 8192 + tid * 16, physB1 = 12288 + tid * 16;
  const int LA0 = swz(tid * 16), LA1 = swz(4096 + tid * 16);
  const unsigned char* pA0 = Aimg + (size_t)(brow + (LA0 >> 6)) * 1024 + (LA0 & 63);
  const unsigned char* pA1 = Aimg + (size_t)(brow + (LA1 >> 6)) * 1024 + (LA1 & 63);
  const unsigned char* pB0 = Bimg + (size_t)(bcol + (LA0 >> 6)) * 1024 + (LA0 & 63);
  const unsigned char* pB1 = Bimg + (size_t)(bcol + (LA1 >> 6)) * 1024 + (LA1 & 63);

  const int s16 = (lane >> 4) * 16;
  int offA[4], offB[4];
#pragma unroll
  for (int m = 0; m < 4; ++m)
    offA[m] = swz((wr * 64 + m * 16 + (lane & 15)) * 64 + s16);
#pragma unroll
  for (int n = 0; n < 4; ++n)
    offB[n] = 8192 + swz((wc * 64 + n * 16 + (lane & 15)) * 64 + s16);

  f32x4 acc[4][4] = {};
  i64x2 af[4], bfE[4], bfO[4];

  auto STAGE = [&](int q) {
    unsigned char* sb = lds + (q % 3) * SLOT;
    const size_t kb = (size_t)q * 64;
    load_lds16(pA0 + kb, sb + physA0);
    load_lds16(pA1 + kb, sb + physA1);
    load_lds16(pB0 + kb, sb + physB0);
    load_lds16(pB1 + kb, sb + physB1);
  };

  // prologue: slots 0,1,2 issued (12 loads/wave); vmcnt(4) retires slots 0,1
  STAGE(0); STAGE(1); STAGE(2);
  asm volatile("s_waitcnt vmcnt(4)" ::: "memory");
  __builtin_amdgcn_s_barrier();
#pragma unroll
  for (int n = 0; n < 4; ++n) bfE[n] = *reinterpret_cast<const i64x2*>(lds + offB[n]);
#pragma unroll
  for (int m = 0; m < 4; ++m) af[m] = *reinterpret_cast<const i64x2*>(lds + offA[m]);
  asm volatile("s_waitcnt lgkmcnt(0)" ::: "memory");
  __builtin_amdgcn_sched_barrier(0);
  __builtin_amdgcn_s_barrier();  // slot 0 free from here
  __builtin_amdgcn_sched_barrier(0);

  // phases 0..11: stage p+3, vmcnt(4)
  for (int pp = 0; pp < 6; ++pp) {
    const int p = 2 * pp;
    const unsigned char* sl1 = lds + ((p + 1) % 3) * SLOT;
    const unsigned char* sl2 = lds + ((p + 2) % 3) * SLOT;
    KPHASE8(bfE, bfO, sl1, p + 3, true, "s_waitcnt vmcnt(4) lgkmcnt(0)", true);
    KPHASE8(bfO, bfE, sl2, p + 4, true, "s_waitcnt vmcnt(4) lgkmcnt(0)", true);
  }
  // p=12: stage 15, vmcnt(4) retires stage(14); p=13: vmcnt(0) retires stage(15)
  KPHASE8(bfE, bfO, lds + (13 % 3) * SLOT, 15, true, "s_waitcnt vmcnt(4) lgkmcnt(0)", true);
  KPHASE8(bfO, bfE, lds + (14 % 3) * SLOT, 0, false, "s_waitcnt vmcnt(0) lgkmcnt(0)", true);
  // p=14: reads frags(15), lgkm only, no barrier (no pending LDS writes)
  KPHASE8(bfE, bfO, lds + (15 % 3) * SLOT, 0, false, "s_waitcnt lgkmcnt(0)", false);
  // p=15: MFMA only
  __builtin_amdgcn_s_setprio(1);
#pragma unroll
  for (int m = 0; m < 4; ++m) {
#pragma unroll
    for (int n = 0; n < 4; ++n)
      acc[m][n] = __builtin_amdgcn_mfma_f32_16x16x32_fp8_fp8(af[m][0], bfO[n][0], acc[m][n], 0, 0, 0);
#pragma unroll
    for (int n = 0; n < 4; ++n)
      acc[m][n] = __builtin_amdgcn_mfma_f32_16x16x32_fp8_fp8(af[m][1], bfO[n][1], acc[m][n], 0, 0, 0);
  }
  __builtin_amdgcn_s_setprio(0);

  // ---- epilogue: proj = acc/512 ; stage bf16 tile (128x128, stride 132)
  __syncthreads();
  unsigned short* cs = (unsigned short*)lds;
  {
    const float inv = 1.0f / 512.0f;
    const int c0 = wc * 64 + (lane & 15);
    const int r00 = wr * 64 + ((lane >> 4) << 2);
#pragma unroll
    for (int m = 0; m < 4; ++m)
#pragma unroll
      for (int n = 0; n < 4; ++n) {
        const int rr = r00 + m * 16, cc = c0 + n * 16;
#pragma unroll
        for (int r = 0; r < 4; ++r) cs[(rr + r) * 132 + cc] = f2b(acc[m][n][r] * inv);
      }
  }
  __syncthreads();

  // ---- fused gates: 128 rows x 32 h per block -> 1024 quads, 4 iters
  const int hbase = bcol >> 2;
#pragma unroll 2
  for (int j = 0; j < 4; ++j) {
    const int v = tid + (j << 8);   // 0..1023
    const int row = v >> 3;         // 0..127
    const int h4 = (v & 7) << 2;    // 0..28
    const int ci = (brow + row) * 1024 + hbase + h4;

    unsigned short pvv[16], xvv[16];
    *reinterpret_cast<uint4*>(&pvv[0]) = *reinterpret_cast<const uint4*>(&cs[row * 132 + h4 * 4]);
    *reinterpret_cast<uint4*>(&pvv[8]) = *reinterpret_cast<const uint4*>(&cs[row * 132 + h4 * 4 + 8]);
    const unsigned short* xr = &xpb_r[(size_t)(brow + row) * N + bcol + h4 * 4];
    *reinterpret_cast<uint4*>(&xvv[0]) = *reinterpret_cast<const uint4*>(xr);
    *reinterpret_cast<uint4*>(&xvv[8]) = *reinterpret_cast<const uint4*>(xr + 8);

    const ushort4 cv = *reinterpret_cast<const ushort4*>(&ct[ci]);
    float c_old[4] = {b2f(cv.x), b2f(cv.y), b2f(cv.z), b2f(cv.w)};

    float cn[4], hn[4];
#pragma unroll
    for (int k = 0; k < 4; ++k) {
      const float f = sigm(b2f(pvv[4 * k + 0]) + b2f(xvv[4 * k + 0]));
      const float ii = sigm(b2f(pvv[4 * k + 1]) + b2f(xvv[4 * k + 1]));
      const float o = sigm(b2f(pvv[4 * k + 2]) + b2f(xvv[4 * k + 2]));
      const float gg = tanh_fast(b2f(pvv[4 * k + 3]) + b2f(xvv[4 * k + 3]));
      const float c = fmaf(f, c_old[k], ii * gg);
      cn[k] = c;
      hn[k] = o * tanh_fast(c);
    }

    if constexpr (LAST) {
      *reinterpret_cast<float4*>(&out[ci]) = make_float4(hn[0], hn[1], hn[2], hn[3]);
      *reinterpret_cast<float4*>(&out[4194304 + ci]) = make_float4(cn[0], cn[1], cn[2], cn[3]);
    } else {
      ushort4 cb;
      cb.x = f2b(cn[0]); cb.y = f2b(cn[1]); cb.z = f2b(cn[2]); cb.w = f2b(cn[3]);
      *reinterpret_cast<ushort4*>(&ct[ci]) = cb;
      const int hc0 = hbase + h4;
      uchar4 h8;
      h8.x = f2fp8(hn[0] * 16.f); h8.y = f2fp8(hn[1] * 16.f);
      h8.z = f2fp8(hn[2] * 16.f); h8.w = f2fp8(hn[3] * 16.f);
      *reinterpret_cast<uchar4*>(&htimg[(size_t)(brow + row) * 1024 + imgk(hc0)]) = h8;
    }
  }
}

// ---------------------------------------------------------------- launch
extern "C" void kernel_launch(void* const* d_in, const int* in_sizes, int n_in,
                              void* d_out, int out_size, void* d_ws, size_t ws_size,
                              hipStream_t stream) {
  const float* x = (const float*)d_in[0];
  const float* W = (const float*)d_in[1];
  const float* bW = (const float*)d_in[2];
  const float* U = (const float*)d_in[3];
  const float* bU = (const float*)d_in[4];
  float* out = (float*)d_out;

  char* w = (char*)d_ws;
  const size_t MB = 1ull << 20;
  unsigned short* xb = (unsigned short*)(w + 0 * MB);    // 8 MB bf16
  unsigned short* Wbp = (unsigned short*)(w + 8 * MB);   // 8 MB bf16 (gate-interleaved)
  unsigned char* Up8 = (unsigned char*)(w + 16 * MB);    // 4 MB fp8 image (x32)
  unsigned short* xpb = (unsigned short*)(w + 24 * MB);  // 32 MB bf16 proj+bias
  unsigned short* ct = (unsigned short*)(w + 56 * MB);   // 8 MB bf16 state
  unsigned char* htA = (unsigned char*)(w + 64 * MB);    // 4 MB fp8 image (x16)
  unsigned char* htB = (unsigned char*)(w + 68 * MB);    // 4 MB fp8 image
  float* bp = (float*)(w + 72 * MB);                     // 16 KB

  prep_kernel<<<9232, 256, 0, stream>>>(x, W, U, bW, bU, xb, Wbp, Up8, bp);

  gemm_x<<<256, 512, 0, stream>>>(xb, Wbp, xpb, bp, ct, htA);

  const unsigned char* hin = htA;
  unsigned char* hout = htB;
  for (int t = 1; t <= 6; ++t) {
    gemm_r<false><<<1024, 256, 0, stream>>>(hin, Up8, xpb, ct, hout, nullptr);
    const unsigned char* tmp = hout;
    hout = (unsigned char*)hin;
    hin = tmp;
  }
  gemm_r<true><<<1024, 256, 0, stream>>>(hin, Up8, xpb, ct, nullptr, out);
}